// Round 11
// baseline (195.563 us; speedup 1.0000x reference)
//
#include <hip/hip_runtime.h>
#include <math.h>

typedef unsigned short u16;
typedef unsigned int u32;
typedef __attribute__((ext_vector_type(8))) short s8v;   // 8 bf16 (4 VGPRs)
typedef __attribute__((ext_vector_type(4))) float f4v;   // MFMA acc

#define KNBR 32
#define MFMA16(a, b, c) __builtin_amdgcn_mfma_f32_16x16x32_bf16((a), (b), (c), 0, 0, 0)

__device__ __forceinline__ float bf2f(u16 u) { return __uint_as_float((u32)u << 16); }
__device__ __forceinline__ float bflo(u32 u) { return __uint_as_float(u << 16); }
__device__ __forceinline__ float bfhi(u32 u) { return __uint_as_float(u & 0xffff0000u); }
__device__ __forceinline__ u16 f2bf(float f) {
    u32 u = __float_as_uint(f);
    return (u16)((u + 0x7fffu + ((u >> 16) & 1u)) >> 16);
}
__device__ __forceinline__ u32 pk2(float a, float b) {
    return (u32)f2bf(a) | ((u32)f2bf(b) << 16);
}
__device__ __forceinline__ float leaky(float v) { return v >= 0.f ? v : 0.1f * v; }
__device__ __forceinline__ float sigm(float v) { return 1.f / (1.f + expf(-v)); }

__device__ __forceinline__ int swz_plb(int b, int full) {
    if (!full) return b << 6;
    int xcd = b & 7;
    int within = ((b >> 3) << 1) | (xcd & 1);
    return ((xcd >> 1) << 13) + (within << 6);
}

// Pre-packed B-frag tables in ws (u32 words, offsets from TB):
// T1 @0     [2][64][68]  W1 g0,g1   (8704)
// T2 @8704  [64][68]     W1 g2      (4352)
// T3 @13056 [2][64][36]  W2 g0,g1   (4608)
// T4 @17664 [2][64][36]  W3 g0,g1   (4608)
// T5 @22272 [64][36]     W2 g2      (2304)
// T6 @24576 [64][36]     W3 g2      (2304)   total 26880
#define T2O 8704
#define T3O 13056
#define T4O 17664
#define T5O 22272
#define T6O 24576
#define TTOT 26880

__global__ __launch_bounds__(512) void k_prep(
    const float* __restrict__ W1f, const float* __restrict__ W2f,
    const float* __restrict__ W3f, u32* __restrict__ TB)
{
    int id = blockIdx.x * 512 + threadIdx.x;
    if (id >= TTOT) return;
    u32 word = 0;
    if (id < T2O) {                      // T1
        int g = id / 4352, r = id - g * 4352;
        int n = r / 68, kp = r - n * 68;
        if (kp < 64)
            word = pk2(W1f[g * 8384 + kp * 128 + n], W1f[g * 8384 + kp * 128 + 64 + n]);
    } else if (id < T3O) {               // T2
        int r = id - T2O;
        int n = r / 68, kp = r - n * 68;
        if (kp < 64)
            word = pk2(W1f[16768 + kp * 128 + n], W1f[16768 + kp * 128 + 64 + n]);
    } else if (id < T4O) {               // T3
        int r = id - T3O;
        int g = r / 2304, r2 = r - g * 2304;
        int n = r2 / 36, kp = r2 - n * 36;
        if (kp < 32)
            word = pk2(W2f[g * 4096 + kp * 128 + n], W2f[g * 4096 + kp * 128 + 64 + n]);
    } else if (id < T5O) {               // T4
        int r = id - T4O;
        int g = r / 2304, r2 = r - g * 2304;
        int n = r2 / 36, kp = r2 - n * 36;
        if (kp < 32)
            word = pk2(W3f[g * 4096 + kp * 128 + n], W3f[g * 4096 + kp * 128 + 64 + n]);
    } else if (id < T6O) {               // T5
        int r = id - T5O;
        int n = r / 36, kp = r - n * 36;
        if (kp < 32)
            word = pk2(W2f[8192 + kp * 128 + n], W2f[8192 + kp * 128 + 64 + n]);
    } else {                             // T6
        int r = id - T6O;
        int n = r / 36, kp = r - n * 36;
        if (kp < 32)
            word = pk2(W3f[8192 + kp * 128 + n], W3f[8192 + kp * 128 + 64 + n]);
    }
    TB[id] = word;
}

// MFMA frags: A[m=lane&15][k=quad*8+j]; B[k=quad*8+j][n=lane&15];
// D: col(n)=lane&15, row(m)=quad*4+reg.

// ---------------- K_A: P01 = [h|x] @ W1[0,1] + b1 ----------------
__global__ __launch_bounds__(512) void k_gemm_p01(
    const float* __restrict__ h, const float* __restrict__ x,
    const u32* __restrict__ TB, const float* __restrict__ b1f,
    u32* __restrict__ P01, int p0, int full)
{
    __shared__ u32 a_lds[64 * 68];
    __shared__ u32 wb[8704];
    int t = threadIdx.x;
    int plb = swz_plb(blockIdx.x, full);
    int pgb = p0 + plb;
    for (int i = 0; i < 8; ++i) {
        int id = t + i * 512;
        int p = id >> 6, cw = id & 63;
        const float* src = (cw < 32) ? (h + (size_t)(pgb + p) * 64 + cw * 2)
                                     : (x + (size_t)(pgb + p) * 64 + (cw - 32) * 2);
        float2 v = *(const float2*)src;
        a_lds[p * 68 + cw] = pk2(v.x, v.y);
    }
    for (int i = 0; i < 17; ++i) wb[t + i * 512] = TB[t + i * 512];   // T1 copy
    __syncthreads();
    int lane = t & 63;
    int w = __builtin_amdgcn_readfirstlane(t >> 6);
    int m = w & 3, npair = w >> 2;
    int quad = lane >> 4, l15 = lane & 15;
    f4v acc[2][2];
    #pragma unroll
    for (int g = 0; g < 2; ++g)
        #pragma unroll
        for (int nt = 0; nt < 2; ++nt) {
            float b = b1f[g * 64 + (npair * 2 + nt) * 16 + l15];
            acc[g][nt] = (f4v){b, b, b, b};
        }
    #pragma unroll
    for (int kb = 0; kb < 4; ++kb) {
        s8v af = *(const s8v*)&a_lds[(m * 16 + l15) * 68 + kb * 16 + quad * 4];
        #pragma unroll
        for (int g = 0; g < 2; ++g)
            #pragma unroll
            for (int nt = 0; nt < 2; ++nt) {
                s8v bf = *(const s8v*)&wb[(g * 64 + (npair * 2 + nt) * 16 + l15) * 68
                                          + kb * 16 + quad * 4];
                acc[g][nt] = MFMA16(af, bf, acc[g][nt]);
            }
    }
    #pragma unroll
    for (int nt = 0; nt < 2; ++nt)
        #pragma unroll
        for (int r = 0; r < 4; ++r) {
            int pt = m * 16 + quad * 4 + r;
            int ch = (npair * 2 + nt) * 16 + l15;
            P01[(size_t)(plb + pt) * 64 + ch] = pk2(acc[0][nt][r], acc[1][nt][r]);
        }
}

// ---------------- K_B: pool01 + MLP(g0,g1) + gemm_p2 ----------------
__global__ __launch_bounds__(512) void k_fuse01(
    const u32* __restrict__ P01, const float* __restrict__ W1f,
    const u32* __restrict__ TB,
    const int* __restrict__ nidx, const float* __restrict__ ef,
    const float* __restrict__ h, const float* __restrict__ x,
    const float* __restrict__ b1f, const float* __restrict__ b2f,
    const float* __restrict__ b3f,
    u16* __restrict__ Z, float* __restrict__ P2, int p0, int full)
{
    __shared__ u32 a_lds[64 * 68];
    __shared__ u32 wb[4608];
    __shared__ u32 idx_l[2048];
    __shared__ u32 ef_p[2048];
    __shared__ float ef2f[2048];
    int t = threadIdx.x;
    int plb = swz_plb(blockIdx.x, full);
    int pg0 = p0 + plb;
    int rbase = ((pg0 >> 13) << 13) - p0;
    int lane = t & 63;
    int w = __builtin_amdgcn_readfirstlane(t >> 6);
    int quad = lane >> 4, l15 = lane & 15;
    u16* y16 = (u16*)a_lds;

    for (int i = 0; i < 9; ++i) wb[t + i * 512] = TB[T3O + t + i * 512];  // W2 frags
    for (int i = 0; i < 4; ++i) {        // neighbor rows (pre-based)
        int cell = t + i * 512;
        int pt = cell >> 5, k = cell & 31;
        idx_l[cell] = (u32)(rbase + nidx[(size_t)(pg0 + pt) * KNBR + k]);
    }
    for (int i = 0; i < 4; ++i) {        // edge feats packed
        int cell = t + i * 512;
        int pt = cell >> 5, k = cell & 31;
        const float* e = ef + ((size_t)(pg0 + pt) * KNBR + k) * 3;
        ef_p[cell] = pk2(e[0], e[1]);
        ef2f[cell] = e[2];
    }
    __syncthreads();
    {   // pool: wave w pools points w*8..w*8+7 (lane = channel)
        float w00 = W1f[8192 + lane], w01 = W1f[8256 + lane], w02 = W1f[8320 + lane];
        float w10 = W1f[16576 + lane], w11 = W1f[16640 + lane], w12 = W1f[16704 + lane];
        for (int pp = 0; pp < 8; ++pp) {
            int lp = w * 8 + pp;
            const u32* ib = &idx_l[lp * 32];
            const u32* eb = &ef_p[lp * 32];
            const float* e2b = &ef2f[lp * 32];
            float m0 = -1e30f, m1 = -1e30f;
            #pragma unroll 16
            for (int k = 0; k < KNBR; ++k) {
                u32 row = ib[k];
                u32 gv = P01[(size_t)row * 64 + lane];
                u32 ew = eb[k];
                float e0 = bflo(ew), e1 = bfhi(ew), e2 = e2b[k];
                m0 = fmaxf(m0, bflo(gv) + e0 * w00 + e1 * w01 + e2 * w02);
                m1 = fmaxf(m1, bfhi(gv) + e0 * w10 + e1 * w11 + e2 * w12);
            }
            y16[lp * 136 + lane]      = f2bf(leaky(m0));
            y16[lp * 136 + 64 + lane] = f2bf(leaky(m1));
        }
    }
    __syncthreads();
    int m = w & 3, g = w >> 2;
    f4v acc[4];
    #pragma unroll
    for (int nt = 0; nt < 4; ++nt) {
        float b = b2f[g * 64 + nt * 16 + l15];
        acc[nt] = (f4v){b, b, b, b};
    }
    #pragma unroll
    for (int kb = 0; kb < 2; ++kb) {     // L1
        s8v af = *(const s8v*)&a_lds[(m * 16 + l15) * 68 + g * 32 + kb * 16 + quad * 4];
        #pragma unroll
        for (int nt = 0; nt < 4; ++nt) {
            s8v bf = *(const s8v*)&wb[(g * 64 + nt * 16 + l15) * 36 + kb * 16 + quad * 4];
            acc[nt] = MFMA16(af, bf, acc[nt]);
        }
    }
    #pragma unroll
    for (int nt = 0; nt < 4; ++nt)
        #pragma unroll
        for (int r = 0; r < 4; ++r)
            y16[(m * 16 + quad * 4 + r) * 136 + g * 64 + nt * 16 + l15] =
                f2bf(leaky(acc[nt][r]));
    __syncthreads();
    for (int i = 0; i < 9; ++i) wb[t + i * 512] = TB[T4O + t + i * 512];  // W3 frags
    __syncthreads();
    #pragma unroll
    for (int nt = 0; nt < 4; ++nt) {
        float b = b3f[g * 64 + nt * 16 + l15];
        acc[nt] = (f4v){b, b, b, b};
    }
    #pragma unroll
    for (int kb = 0; kb < 2; ++kb) {     // L2
        s8v af = *(const s8v*)&a_lds[(m * 16 + l15) * 68 + g * 32 + kb * 16 + quad * 4];
        #pragma unroll
        for (int nt = 0; nt < 4; ++nt) {
            s8v bf = *(const s8v*)&wb[(g * 64 + nt * 16 + l15) * 36 + kb * 16 + quad * 4];
            acc[nt] = MFMA16(af, bf, acc[nt]);
        }
    }
    __syncthreads();
    if (g == 0) {                        // Z -> global
        #pragma unroll
        for (int nt = 0; nt < 4; ++nt)
            #pragma unroll
            for (int r = 0; r < 4; ++r) {
                int pt = m * 16 + quad * 4 + r;
                int ch = nt * 16 + l15;
                Z[(size_t)(plb + pt) * 64 + ch] = f2bf(sigm(acc[nt][r]));
            }
    } else {                             // RH -> a_lds words 0..31
        #pragma unroll
        for (int nt = 0; nt < 4; ++nt)
            #pragma unroll
            for (int r = 0; r < 4; ++r) {
                int pt = m * 16 + quad * 4 + r;
                int ch = nt * 16 + l15;
                float hv = h[(size_t)(pg0 + pt) * 64 + ch];
                y16[pt * 136 + ch] = f2bf(sigm(acc[nt][r]) * hv);
            }
    }
    for (int i = 0; i < 4; ++i) {        // x -> words 32..63
        int id = t + i * 512;
        int p = id >> 5, cw = id & 31;
        float2 v = *(const float2*)(x + (size_t)(pg0 + p) * 64 + cw * 2);
        a_lds[p * 68 + 32 + cw] = pk2(v.x, v.y);
    }
    for (int i = 0; i < 9; ++i) {        // W1[2] frags (4352 words)
        int id = t + i * 512;
        if (id < 4352) wb[id] = TB[T2O + id];
    }
    __syncthreads();
    int nh = w >> 2;
    f4v pacc[2];
    #pragma unroll
    for (int nt = 0; nt < 2; ++nt) {
        float b = b1f[128 + (nh * 2 + nt) * 16 + l15];
        pacc[nt] = (f4v){b, b, b, b};
    }
    #pragma unroll
    for (int kb = 0; kb < 4; ++kb) {     // K=128 ([RH|x])
        s8v af = *(const s8v*)&a_lds[(m * 16 + l15) * 68 + kb * 16 + quad * 4];
        #pragma unroll
        for (int nt = 0; nt < 2; ++nt) {
            s8v bf = *(const s8v*)&wb[((nh * 2 + nt) * 16 + l15) * 68 + kb * 16 + quad * 4];
            pacc[nt] = MFMA16(af, bf, pacc[nt]);
        }
    }
    #pragma unroll
    for (int nt = 0; nt < 2; ++nt)
        #pragma unroll
        for (int r = 0; r < 4; ++r) {
            int pt = m * 16 + quad * 4 + r;
            int ch = (nh * 2 + nt) * 16 + l15;
            P2[(size_t)(plb + pt) * 64 + ch] = pacc[nt][r];
        }
}

// ---------------- K_C: pool2 + MLP(g2) + GRU epilogue ----------------
__global__ __launch_bounds__(512) void k_fuse2(
    const float* __restrict__ P2, const float* __restrict__ W1f,
    const u32* __restrict__ TB,
    const int* __restrict__ nidx, const float* __restrict__ ef,
    const float* __restrict__ b2f, const float* __restrict__ b3f,
    const float* __restrict__ h, const u16* __restrict__ Z,
    float* __restrict__ out, int p0, int full)
{
    __shared__ u32 a_lds[64 * 36];
    __shared__ u32 wb[2304];
    __shared__ u32 idx_l[2048];
    __shared__ u32 ef_p[2048];
    __shared__ float ef2f[2048];
    int t = threadIdx.x;
    int plb = swz_plb(blockIdx.x, full);
    int pg0 = p0 + plb;
    int rbase = ((pg0 >> 13) << 13) - p0;
    int lane = t & 63;
    int w = __builtin_amdgcn_readfirstlane(t >> 6);
    int quad = lane >> 4, l15 = lane & 15;
    u16* y16 = (u16*)a_lds;

    for (int i = 0; i < 5; ++i) {        // W2[2] frags (2304 words)
        int id = t + i * 512;
        if (id < 2304) wb[id] = TB[T5O + id];
    }
    for (int i = 0; i < 4; ++i) {
        int cell = t + i * 512;
        int pt = cell >> 5, k = cell & 31;
        idx_l[cell] = (u32)(rbase + nidx[(size_t)(pg0 + pt) * KNBR + k]);
    }
    for (int i = 0; i < 4; ++i) {
        int cell = t + i * 512;
        int pt = cell >> 5, k = cell & 31;
        const float* e = ef + ((size_t)(pg0 + pt) * KNBR + k) * 3;
        ef_p[cell] = pk2(e[0], e[1]);
        ef2f[cell] = e[2];
    }
    __syncthreads();
    {   // pool2
        const float* W = W1f + 2 * 8384;
        float w0 = W[8192 + lane], w1 = W[8256 + lane], w2 = W[8320 + lane];
        for (int pp = 0; pp < 8; ++pp) {
            int lp = w * 8 + pp;
            const u32* ib = &idx_l[lp * 32];
            const u32* eb = &ef_p[lp * 32];
            const float* e2b = &ef2f[lp * 32];
            float m = -1e30f;
            #pragma unroll 16
            for (int k = 0; k < KNBR; ++k) {
                u32 row = ib[k];
                float gv = P2[(size_t)row * 64 + lane];
                u32 ew = eb[k];
                float e0 = bflo(ew), e1 = bfhi(ew), e2 = e2b[k];
                m = fmaxf(m, gv + e0 * w0 + e1 * w1 + e2 * w2);
            }
            y16[lp * 72 + lane] = f2bf(leaky(m));
        }
    }
    __syncthreads();
    int m = w & 3, nh = w >> 2;
    f4v acc[2];
    #pragma unroll
    for (int nt = 0; nt < 2; ++nt) {
        float b = b2f[128 + (nh * 2 + nt) * 16 + l15];
        acc[nt] = (f4v){b, b, b, b};
    }
    #pragma unroll
    for (int kb = 0; kb < 2; ++kb) {     // L1
        s8v af = *(const s8v*)&a_lds[(m * 16 + l15) * 36 + kb * 16 + quad * 4];
        #pragma unroll
        for (int nt = 0; nt < 2; ++nt) {
            s8v bf = *(const s8v*)&wb[((nh * 2 + nt) * 16 + l15) * 36 + kb * 16 + quad * 4];
            acc[nt] = MFMA16(af, bf, acc[nt]);
        }
    }
    __syncthreads();
    #pragma unroll
    for (int nt = 0; nt < 2; ++nt)
        #pragma unroll
        for (int r = 0; r < 4; ++r)
            y16[(m * 16 + quad * 4 + r) * 72 + (nh * 2 + nt) * 16 + l15] =
                f2bf(leaky(acc[nt][r]));
    for (int i = 0; i < 5; ++i) {        // W3[2] frags
        int id = t + i * 512;
        if (id < 2304) wb[id] = TB[T6O + id];
    }
    __syncthreads();
    #pragma unroll
    for (int nt = 0; nt < 2; ++nt) {
        float b = b3f[128 + (nh * 2 + nt) * 16 + l15];
        acc[nt] = (f4v){b, b, b, b};
    }
    #pragma unroll
    for (int kb = 0; kb < 2; ++kb) {     // L2
        s8v af = *(const s8v*)&a_lds[(m * 16 + l15) * 36 + kb * 16 + quad * 4];
        #pragma unroll
        for (int nt = 0; nt < 2; ++nt) {
            s8v bf = *(const s8v*)&wb[((nh * 2 + nt) * 16 + l15) * 36 + kb * 16 + quad * 4];
            acc[nt] = MFMA16(af, bf, acc[nt]);
        }
    }
    #pragma unroll
    for (int nt = 0; nt < 2; ++nt)
        #pragma unroll
        for (int r = 0; r < 4; ++r) {
            int pt = m * 16 + quad * 4 + r;
            int ch = (nh * 2 + nt) * 16 + l15;
            int pl = plb + pt;
            int pg = p0 + pl;
            float z = bf2f(Z[(size_t)pl * 64 + ch]);
            float hv = h[(size_t)pg * 64 + ch];
            out[(size_t)pg * 64 + ch] = (1.f - z) * hv + z * tanhf(acc[nt][r]);
        }
}

extern "C" void kernel_launch(void* const* d_in, const int* in_sizes, int n_in,
                              void* d_out, int out_size, void* d_ws, size_t ws_size,
                              hipStream_t stream)
{
    const float* h  = (const float*)d_in[0];
    const float* x  = (const float*)d_in[1];
    // d_in[2] = c (unused by the reference)
    const float* W1 = (const float*)d_in[3];
    const float* b1 = (const float*)d_in[4];
    const float* W2 = (const float*)d_in[5];
    const float* b2 = (const float*)d_in[6];
    const float* W3 = (const float*)d_in[7];
    const float* b3 = (const float*)d_in[8];
    const int* nidx = (const int*)d_in[9];
    const float* ef = (const float*)d_in[10];
    float* out = (float*)d_out;

    char* wsb = (char*)d_ws;
    size_t need_full = 32768ull * 640ull + (size_t)TTOT * 4ull;
    size_t PN = (ws_size >= need_full) ? 32768 : 8192;
    int passes = (int)(32768 / PN);
    int full = (PN == 32768) ? 1 : 0;

    u32* P01  = (u32*)wsb;                  // [PN][64] u32 (gate-interleaved bf16 pair)
    u16* Z    = (u16*)(wsb + PN * 256);     // [PN][64] bf16
    float* P2 = (float*)(wsb + PN * 384);   // [PN][64] f32
    u32* TB   = (u32*)(wsb + PN * 640);     // packed weight-frag tables

    k_prep<<<dim3((TTOT + 511) / 512), 512, 0, stream>>>(W1, W2, W3, TB);
    for (int s = 0; s < passes; ++s) {
        int p0 = (int)(s * PN);
        dim3 g((unsigned)(PN / 64));
        k_gemm_p01<<<g, 512, 0, stream>>>(h, x, TB, b1, P01, p0, full);
        k_fuse01  <<<g, 512, 0, stream>>>(P01, W1, TB, nidx, ef, h, x,
                                          b1, b2, b3, Z, P2, p0, full);
        k_fuse2   <<<g, 512, 0, stream>>>(P2, W1, TB, nidx, ef,
                                          b2, b3, h, Z, out, p0, full);
    }
}

// Round 12
// 164.252 us; speedup vs baseline: 1.1906x; 1.1906x over previous
//
#include <hip/hip_runtime.h>
#include <math.h>

typedef unsigned short u16;
typedef unsigned int u32;
typedef __attribute__((ext_vector_type(8))) short s8v;   // 8 bf16 (4 VGPRs)
typedef __attribute__((ext_vector_type(4))) float f4v;   // MFMA acc

#define KNBR 32
#define MFMA16(a, b, c) __builtin_amdgcn_mfma_f32_16x16x32_bf16((a), (b), (c), 0, 0, 0)

__device__ __forceinline__ float bf2f(u16 u) { return __uint_as_float((u32)u << 16); }
__device__ __forceinline__ float bflo(u32 u) { return __uint_as_float(u << 16); }
__device__ __forceinline__ float bfhi(u32 u) { return __uint_as_float(u & 0xffff0000u); }
__device__ __forceinline__ u16 f2bf(float f) {
    u32 u = __float_as_uint(f);
    return (u16)((u + 0x7fffu + ((u >> 16) & 1u)) >> 16);
}
__device__ __forceinline__ u32 pk2(float a, float b) {
    return (u32)f2bf(a) | ((u32)f2bf(b) << 16);
}
__device__ __forceinline__ float leaky(float v) { return v >= 0.f ? v : 0.1f * v; }
__device__ __forceinline__ float sigm(float v) { return 1.f / (1.f + expf(-v)); }

__device__ __forceinline__ int swz_plb(int b, int full) {
    if (!full) return b << 6;
    int xcd = b & 7;
    int within = ((b >> 3) << 1) | (xcd & 1);
    return ((xcd >> 1) << 13) + (within << 6);
}

// Pre-packed B-frag tables in ws (u32 words, offsets from TB):
#define T2O 8704
#define T3O 13056
#define T4O 17664
#define T5O 22272
#define T6O 24576
#define TTOT 26880

__global__ __launch_bounds__(512) void k_prep(
    const float* __restrict__ W1f, const float* __restrict__ W2f,
    const float* __restrict__ W3f, u32* __restrict__ TB)
{
    int id = blockIdx.x * 512 + threadIdx.x;
    if (id >= TTOT) return;
    u32 word = 0;
    if (id < T2O) {                      // T1: W1 g0,g1 [2][64][68]
        int g = id / 4352, r = id - g * 4352;
        int n = r / 68, kp = r - n * 68;
        if (kp < 64)
            word = pk2(W1f[g * 8384 + kp * 128 + n], W1f[g * 8384 + kp * 128 + 64 + n]);
    } else if (id < T3O) {               // T2: W1 g2 [64][68]
        int r = id - T2O;
        int n = r / 68, kp = r - n * 68;
        if (kp < 64)
            word = pk2(W1f[16768 + kp * 128 + n], W1f[16768 + kp * 128 + 64 + n]);
    } else if (id < T4O) {               // T3: W2 g0,g1 [2][64][36]
        int r = id - T3O;
        int g = r / 2304, r2 = r - g * 2304;
        int n = r2 / 36, kp = r2 - n * 36;
        if (kp < 32)
            word = pk2(W2f[g * 4096 + kp * 128 + n], W2f[g * 4096 + kp * 128 + 64 + n]);
    } else if (id < T5O) {               // T4: W3 g0,g1
        int r = id - T4O;
        int g = r / 2304, r2 = r - g * 2304;
        int n = r2 / 36, kp = r2 - n * 36;
        if (kp < 32)
            word = pk2(W3f[g * 4096 + kp * 128 + n], W3f[g * 4096 + kp * 128 + 64 + n]);
    } else if (id < T6O) {               // T5: W2 g2
        int r = id - T5O;
        int n = r / 36, kp = r - n * 36;
        if (kp < 32)
            word = pk2(W2f[8192 + kp * 128 + n], W2f[8192 + kp * 128 + 64 + n]);
    } else {                             // T6: W3 g2
        int r = id - T6O;
        int n = r / 36, kp = r - n * 36;
        if (kp < 32)
            word = pk2(W3f[8192 + kp * 128 + n], W3f[8192 + kp * 128 + 64 + n]);
    }
    TB[id] = word;
}

// MFMA frags: A[m=lane&15][k=quad*8+j]; B[k=quad*8+j][n=lane&15];
// D: col(n)=lane&15, row(m)=quad*4+reg.

// ---------------- K_A: P01 = [h|x] @ W1[0,1] + b1 ----------------
__global__ __launch_bounds__(512) void k_gemm_p01(
    const float* __restrict__ h, const float* __restrict__ x,
    const u32* __restrict__ TB, const float* __restrict__ b1f,
    u32* __restrict__ P01, int p0, int full)
{
    __shared__ u32 a_lds[64 * 68];
    __shared__ u32 wb[8704];
    int t = threadIdx.x;
    int plb = swz_plb(blockIdx.x, full);
    int pgb = p0 + plb;
    for (int i = 0; i < 8; ++i) {
        int id = t + i * 512;
        int p = id >> 6, cw = id & 63;
        const float* src = (cw < 32) ? (h + (size_t)(pgb + p) * 64 + cw * 2)
                                     : (x + (size_t)(pgb + p) * 64 + (cw - 32) * 2);
        float2 v = *(const float2*)src;
        a_lds[p * 68 + cw] = pk2(v.x, v.y);
    }
    for (int i = 0; i < 17; ++i) wb[t + i * 512] = TB[t + i * 512];
    __syncthreads();
    int lane = t & 63;
    int w = __builtin_amdgcn_readfirstlane(t >> 6);
    int m = w & 3, npair = w >> 2;
    int quad = lane >> 4, l15 = lane & 15;
    f4v acc[2][2];
    #pragma unroll
    for (int g = 0; g < 2; ++g)
        #pragma unroll
        for (int nt = 0; nt < 2; ++nt) {
            float b = b1f[g * 64 + (npair * 2 + nt) * 16 + l15];
            acc[g][nt] = (f4v){b, b, b, b};
        }
    #pragma unroll
    for (int kb = 0; kb < 4; ++kb) {
        s8v af = *(const s8v*)&a_lds[(m * 16 + l15) * 68 + kb * 16 + quad * 4];
        #pragma unroll
        for (int g = 0; g < 2; ++g)
            #pragma unroll
            for (int nt = 0; nt < 2; ++nt) {
                s8v bf = *(const s8v*)&wb[(g * 64 + (npair * 2 + nt) * 16 + l15) * 68
                                          + kb * 16 + quad * 4];
                acc[g][nt] = MFMA16(af, bf, acc[g][nt]);
            }
    }
    #pragma unroll
    for (int nt = 0; nt < 2; ++nt)
        #pragma unroll
        for (int r = 0; r < 4; ++r) {
            int pt = m * 16 + quad * 4 + r;
            int ch = (npair * 2 + nt) * 16 + l15;
            P01[(size_t)(plb + pt) * 64 + ch] = pk2(acc[0][nt][r], acc[1][nt][r]);
        }
}

// ---------------- K_B: pool01 + MLP(g0,g1) + gemm_p2 ----------------
__global__ __launch_bounds__(512) void k_fuse01(
    const u32* __restrict__ P01, const float* __restrict__ W1f,
    const u32* __restrict__ TB,
    const int* __restrict__ nidx, const float* __restrict__ ef,
    const float* __restrict__ h, const float* __restrict__ x,
    const float* __restrict__ b1f, const float* __restrict__ b2f,
    const float* __restrict__ b3f,
    u16* __restrict__ Z, float* __restrict__ P2, int p0, int full)
{
    __shared__ u32 a_lds[64 * 68];      // 17408 B
    __shared__ u32 wb[4608];            // 18432 B
    __shared__ u32 idx_l[1024];         // u16 row pairs, 4096 B
    __shared__ u32 ef_p[2048];          // pk2(e0,e1) per cell, 8192 B
    __shared__ u32 e2_p[1024];          // pk2(e2_even, e2_odd), 4096 B  -> total 52224 B
    int t = threadIdx.x;
    int plb = swz_plb(blockIdx.x, full);
    int pg0 = p0 + plb;
    int rbase = ((pg0 >> 13) << 13) - p0;
    int lane = t & 63;
    int w = __builtin_amdgcn_readfirstlane(t >> 6);
    int quad = lane >> 4, l15 = lane & 15;
    u16* y16 = (u16*)a_lds;

    for (int i = 0; i < 9; ++i) wb[t + i * 512] = TB[T3O + t + i * 512];  // W2 frags
    for (int i = 0; i < 2; ++i) {        // idx + edge staging (pair granularity)
        int id = t + i * 512;            // 0..1023
        int pt = id >> 4, k2 = id & 15;
        int2 nn = *(const int2*)(nidx + (size_t)(pg0 + pt) * KNBR + 2 * k2);
        idx_l[id] = (u32)(rbase + nn.x) | ((u32)(rbase + nn.y) << 16);
        const float* e = ef + ((size_t)(pg0 + pt) * KNBR + 2 * k2) * 3;
        float2 a = *(const float2*)(e);
        float2 b = *(const float2*)(e + 2);
        float2 c = *(const float2*)(e + 4);
        uint2 ev; ev.x = pk2(a.x, a.y); ev.y = pk2(b.y, c.x);
        ((uint2*)ef_p)[id] = ev;
        e2_p[id] = pk2(b.x, c.y);
    }
    __syncthreads();
    {   // pool: wave w pools points w*8..w*8+7 (lane = channel), neighbor pairs
        float w00 = W1f[8192 + lane], w01 = W1f[8256 + lane], w02 = W1f[8320 + lane];
        float w10 = W1f[16576 + lane], w11 = W1f[16640 + lane], w12 = W1f[16704 + lane];
        const u32* P01l = P01 + lane;
        for (int pp = 0; pp < 8; ++pp) {
            int lp = w * 8 + pp;
            const u32* ib2 = &idx_l[lp * 16];
            const uint2* eb2 = (const uint2*)&ef_p[lp * 32];
            const u32* e2b = &e2_p[lp * 16];
            float m0 = -1e30f, m1 = -1e30f;
            #pragma unroll
            for (int k2 = 0; k2 < 16; ++k2) {
                u32 rw = ib2[k2];
                uint2 ew = eb2[k2];
                u32 e2w = e2b[k2];
                u32 g0 = P01l[(rw & 0xffffu) * 64];
                u32 g1 = P01l[(rw >> 16) * 64];
                float e00 = bflo(ew.x), e01 = bfhi(ew.x), e02 = bflo(e2w);
                float e10 = bflo(ew.y), e11 = bfhi(ew.y), e12 = bfhi(e2w);
                m0 = fmaxf(m0, bflo(g0) + e00 * w00 + e01 * w01 + e02 * w02);
                m1 = fmaxf(m1, bfhi(g0) + e00 * w10 + e01 * w11 + e02 * w12);
                m0 = fmaxf(m0, bflo(g1) + e10 * w00 + e11 * w01 + e12 * w02);
                m1 = fmaxf(m1, bfhi(g1) + e10 * w10 + e11 * w11 + e12 * w12);
            }
            y16[lp * 136 + lane]      = f2bf(leaky(m0));
            y16[lp * 136 + 64 + lane] = f2bf(leaky(m1));
        }
    }
    __syncthreads();
    int m = w & 3, g = w >> 2;
    f4v acc[4];
    #pragma unroll
    for (int nt = 0; nt < 4; ++nt) {
        float b = b2f[g * 64 + nt * 16 + l15];
        acc[nt] = (f4v){b, b, b, b};
    }
    #pragma unroll
    for (int kb = 0; kb < 2; ++kb) {     // L1
        s8v af = *(const s8v*)&a_lds[(m * 16 + l15) * 68 + g * 32 + kb * 16 + quad * 4];
        #pragma unroll
        for (int nt = 0; nt < 4; ++nt) {
            s8v bf = *(const s8v*)&wb[(g * 64 + nt * 16 + l15) * 36 + kb * 16 + quad * 4];
            acc[nt] = MFMA16(af, bf, acc[nt]);
        }
    }
    #pragma unroll
    for (int nt = 0; nt < 4; ++nt)
        #pragma unroll
        for (int r = 0; r < 4; ++r)
            y16[(m * 16 + quad * 4 + r) * 136 + g * 64 + nt * 16 + l15] =
                f2bf(leaky(acc[nt][r]));
    __syncthreads();
    for (int i = 0; i < 9; ++i) wb[t + i * 512] = TB[T4O + t + i * 512];  // W3 frags
    __syncthreads();
    #pragma unroll
    for (int nt = 0; nt < 4; ++nt) {
        float b = b3f[g * 64 + nt * 16 + l15];
        acc[nt] = (f4v){b, b, b, b};
    }
    #pragma unroll
    for (int kb = 0; kb < 2; ++kb) {     // L2
        s8v af = *(const s8v*)&a_lds[(m * 16 + l15) * 68 + g * 32 + kb * 16 + quad * 4];
        #pragma unroll
        for (int nt = 0; nt < 4; ++nt) {
            s8v bf = *(const s8v*)&wb[(g * 64 + nt * 16 + l15) * 36 + kb * 16 + quad * 4];
            acc[nt] = MFMA16(af, bf, acc[nt]);
        }
    }
    __syncthreads();
    if (g == 0) {
        #pragma unroll
        for (int nt = 0; nt < 4; ++nt)
            #pragma unroll
            for (int r = 0; r < 4; ++r) {
                int pt = m * 16 + quad * 4 + r;
                int ch = nt * 16 + l15;
                Z[(size_t)(plb + pt) * 64 + ch] = f2bf(sigm(acc[nt][r]));
            }
    } else {
        #pragma unroll
        for (int nt = 0; nt < 4; ++nt)
            #pragma unroll
            for (int r = 0; r < 4; ++r) {
                int pt = m * 16 + quad * 4 + r;
                int ch = nt * 16 + l15;
                float hv = h[(size_t)(pg0 + pt) * 64 + ch];
                y16[pt * 136 + ch] = f2bf(sigm(acc[nt][r]) * hv);
            }
    }
    for (int i = 0; i < 4; ++i) {        // x -> words 32..63
        int id = t + i * 512;
        int p = id >> 5, cw = id & 31;
        float2 v = *(const float2*)(x + (size_t)(pg0 + p) * 64 + cw * 2);
        a_lds[p * 68 + 32 + cw] = pk2(v.x, v.y);
    }
    for (int i = 0; i < 9; ++i) {        // W1[2] frags (4352 words)
        int id = t + i * 512;
        if (id < 4352) wb[id] = TB[T2O + id];
    }
    __syncthreads();
    int nh = w >> 2;
    f4v pacc[2];
    #pragma unroll
    for (int nt = 0; nt < 2; ++nt) {
        float b = b1f[128 + (nh * 2 + nt) * 16 + l15];
        pacc[nt] = (f4v){b, b, b, b};
    }
    #pragma unroll
    for (int kb = 0; kb < 4; ++kb) {     // K=128 ([RH|x])
        s8v af = *(const s8v*)&a_lds[(m * 16 + l15) * 68 + kb * 16 + quad * 4];
        #pragma unroll
        for (int nt = 0; nt < 2; ++nt) {
            s8v bf = *(const s8v*)&wb[((nh * 2 + nt) * 16 + l15) * 68 + kb * 16 + quad * 4];
            pacc[nt] = MFMA16(af, bf, pacc[nt]);
        }
    }
    #pragma unroll
    for (int nt = 0; nt < 2; ++nt)
        #pragma unroll
        for (int r = 0; r < 4; ++r) {
            int pt = m * 16 + quad * 4 + r;
            int ch = (nh * 2 + nt) * 16 + l15;
            P2[(size_t)(plb + pt) * 64 + ch] = pacc[nt][r];
        }
}

// ---------------- K_C: pool2 + MLP(g2) + GRU epilogue ----------------
__global__ __launch_bounds__(512) void k_fuse2(
    const float* __restrict__ P2, const float* __restrict__ W1f,
    const u32* __restrict__ TB,
    const int* __restrict__ nidx, const float* __restrict__ ef,
    const float* __restrict__ b2f, const float* __restrict__ b3f,
    const float* __restrict__ h, const u16* __restrict__ Z,
    float* __restrict__ out, int p0, int full)
{
    __shared__ u32 a_lds[64 * 36];      // 9216 B
    __shared__ u32 wb[2304];            // 9216 B
    __shared__ u32 idx_l[1024];
    __shared__ u32 ef_p[2048];
    __shared__ u32 e2_p[1024];          // total 34816 B
    int t = threadIdx.x;
    int plb = swz_plb(blockIdx.x, full);
    int pg0 = p0 + plb;
    int rbase = ((pg0 >> 13) << 13) - p0;
    int lane = t & 63;
    int w = __builtin_amdgcn_readfirstlane(t >> 6);
    int quad = lane >> 4, l15 = lane & 15;
    u16* y16 = (u16*)a_lds;

    for (int i = 0; i < 5; ++i) {        // W2[2] frags
        int id = t + i * 512;
        if (id < 2304) wb[id] = TB[T5O + id];
    }
    for (int i = 0; i < 2; ++i) {
        int id = t + i * 512;
        int pt = id >> 4, k2 = id & 15;
        int2 nn = *(const int2*)(nidx + (size_t)(pg0 + pt) * KNBR + 2 * k2);
        idx_l[id] = (u32)(rbase + nn.x) | ((u32)(rbase + nn.y) << 16);
        const float* e = ef + ((size_t)(pg0 + pt) * KNBR + 2 * k2) * 3;
        float2 a = *(const float2*)(e);
        float2 b = *(const float2*)(e + 2);
        float2 c = *(const float2*)(e + 4);
        uint2 ev; ev.x = pk2(a.x, a.y); ev.y = pk2(b.y, c.x);
        ((uint2*)ef_p)[id] = ev;
        e2_p[id] = pk2(b.x, c.y);
    }
    __syncthreads();
    {   // pool2 (neighbor pairs)
        const float* W = W1f + 2 * 8384;
        float w0 = W[8192 + lane], w1 = W[8256 + lane], w2 = W[8320 + lane];
        const float* P2l = P2 + lane;
        for (int pp = 0; pp < 8; ++pp) {
            int lp = w * 8 + pp;
            const u32* ib2 = &idx_l[lp * 16];
            const uint2* eb2 = (const uint2*)&ef_p[lp * 32];
            const u32* e2b = &e2_p[lp * 16];
            float m = -1e30f;
            #pragma unroll
            for (int k2 = 0; k2 < 16; ++k2) {
                u32 rw = ib2[k2];
                uint2 ew = eb2[k2];
                u32 e2w = e2b[k2];
                float g0 = P2l[(rw & 0xffffu) * 64];
                float g1 = P2l[(rw >> 16) * 64];
                float e00 = bflo(ew.x), e01 = bfhi(ew.x), e02 = bflo(e2w);
                float e10 = bflo(ew.y), e11 = bfhi(ew.y), e12 = bfhi(e2w);
                m = fmaxf(m, g0 + e00 * w0 + e01 * w1 + e02 * w2);
                m = fmaxf(m, g1 + e10 * w0 + e11 * w1 + e12 * w2);
            }
            y16[lp * 72 + lane] = f2bf(leaky(m));
        }
    }
    __syncthreads();
    int m = w & 3, nh = w >> 2;
    f4v acc[2];
    #pragma unroll
    for (int nt = 0; nt < 2; ++nt) {
        float b = b2f[128 + (nh * 2 + nt) * 16 + l15];
        acc[nt] = (f4v){b, b, b, b};
    }
    #pragma unroll
    for (int kb = 0; kb < 2; ++kb) {     // L1
        s8v af = *(const s8v*)&a_lds[(m * 16 + l15) * 36 + kb * 16 + quad * 4];
        #pragma unroll
        for (int nt = 0; nt < 2; ++nt) {
            s8v bf = *(const s8v*)&wb[((nh * 2 + nt) * 16 + l15) * 36 + kb * 16 + quad * 4];
            acc[nt] = MFMA16(af, bf, acc[nt]);
        }
    }
    __syncthreads();
    #pragma unroll
    for (int nt = 0; nt < 2; ++nt)
        #pragma unroll
        for (int r = 0; r < 4; ++r)
            y16[(m * 16 + quad * 4 + r) * 72 + (nh * 2 + nt) * 16 + l15] =
                f2bf(leaky(acc[nt][r]));
    for (int i = 0; i < 5; ++i) {        // W3[2] frags
        int id = t + i * 512;
        if (id < 2304) wb[id] = TB[T6O + id];
    }
    __syncthreads();
    #pragma unroll
    for (int nt = 0; nt < 2; ++nt) {
        float b = b3f[128 + (nh * 2 + nt) * 16 + l15];
        acc[nt] = (f4v){b, b, b, b};
    }
    #pragma unroll
    for (int kb = 0; kb < 2; ++kb) {     // L2
        s8v af = *(const s8v*)&a_lds[(m * 16 + l15) * 36 + kb * 16 + quad * 4];
        #pragma unroll
        for (int nt = 0; nt < 2; ++nt) {
            s8v bf = *(const s8v*)&wb[((nh * 2 + nt) * 16 + l15) * 36 + kb * 16 + quad * 4];
            acc[nt] = MFMA16(af, bf, acc[nt]);
        }
    }
    #pragma unroll
    for (int nt = 0; nt < 2; ++nt)
        #pragma unroll
        for (int r = 0; r < 4; ++r) {
            int pt = m * 16 + quad * 4 + r;
            int ch = (nh * 2 + nt) * 16 + l15;
            int pl = plb + pt;
            int pg = p0 + pl;
            float z = bf2f(Z[(size_t)pl * 64 + ch]);
            float hv = h[(size_t)pg * 64 + ch];
            out[(size_t)pg * 64 + ch] = (1.f - z) * hv + z * tanhf(acc[nt][r]);
        }
}

extern "C" void kernel_launch(void* const* d_in, const int* in_sizes, int n_in,
                              void* d_out, int out_size, void* d_ws, size_t ws_size,
                              hipStream_t stream)
{
    const float* h  = (const float*)d_in[0];
    const float* x  = (const float*)d_in[1];
    // d_in[2] = c (unused by the reference)
    const float* W1 = (const float*)d_in[3];
    const float* b1 = (const float*)d_in[4];
    const float* W2 = (const float*)d_in[5];
    const float* b2 = (const float*)d_in[6];
    const float* W3 = (const float*)d_in[7];
    const float* b3 = (const float*)d_in[8];
    const int* nidx = (const int*)d_in[9];
    const float* ef = (const float*)d_in[10];
    float* out = (float*)d_out;

    char* wsb = (char*)d_ws;
    size_t need_full = 32768ull * 640ull + (size_t)TTOT * 4ull;
    size_t PN = (ws_size >= need_full) ? 32768 : 8192;
    int passes = (int)(32768 / PN);
    int full = (PN == 32768) ? 1 : 0;

    u32* P01  = (u32*)wsb;                  // [PN][64] u32 (gate-interleaved bf16 pair)
    u16* Z    = (u16*)(wsb + PN * 256);     // [PN][64] bf16
    float* P2 = (float*)(wsb + PN * 384);   // [PN][64] f32
    u32* TB   = (u32*)(wsb + PN * 640);     // packed weight-frag tables

    k_prep<<<dim3((TTOT + 511) / 512), 512, 0, stream>>>(W1, W2, W3, TB);
    for (int s = 0; s < passes; ++s) {
        int p0 = (int)(s * PN);
        dim3 g((unsigned)(PN / 64));
        k_gemm_p01<<<g, 512, 0, stream>>>(h, x, TB, b1, P01, p0, full);
        k_fuse01  <<<g, 512, 0, stream>>>(P01, W1, TB, nidx, ef, h, x,
                                          b1, b2, b3, Z, P2, p0, full);
        k_fuse2   <<<g, 512, 0, stream>>>(P2, W1, TB, nidx, ef,
                                          b2, b3, h, Z, out, p0, full);
    }
}